// Round 18
// baseline (78.209 us; speedup 1.0000x reference)
//
#include <hip/hip_runtime.h>

// BatchWiseTripletLoss: n=8192, d=128, 512 classes, scalar output.
// Round-18 = round-17 (triangular sweep, 8 waves x 32 rows, LDS colbuf,
// atomicMax, compact loop) with ONE structural change: each wave-step now
// processes 4 column stripes at once -> 8 independent MFMA accumulator
// chains (acc[4][2]) instead of 2. Rationale: across rounds 10-17 the
// sweep sat at ~40us regardless of occupancy/B-source/pipelining; the one
// invariant was 2 MFMA chains/wave — the ds_read->4-deep-MFMA->epilogue
// serial chain never had intra-wave ILP to hide under.
// launch_bounds(512,2): 256-reg budget; footprint ~125 -> no spill.
// ((256,4)'s and (512,4)'s 128-reg cap spilled in rounds 3/6/11.)

#define D 128
#define NCLS 512
#define CAP 2048               // negative-candidate capacity (expected ~0)
#define PSIM_CAP (512 * 1024)  // sum m^2 ~ 139K expected; 2MB safety
#define MARGIN 0.1f
#define NEG_FLOOR 0.6f
#define NINF -1e30f

typedef short bf16x8 __attribute__((ext_vector_type(8)));
typedef float f32x4 __attribute__((ext_vector_type(4)));

__device__ __forceinline__ unsigned short f2bf(float f) {
  unsigned u = __float_as_uint(f);
  u += 0x7FFFu + ((u >> 16) & 1u);
  return (unsigned short)(u >> 16);
}

// Order-monotonic float<->uint encoding (for atomicMax).
__device__ __forceinline__ unsigned fenc(float f) {
  unsigned u = __float_as_uint(f);
  return (u & 0x80000000u) ? ~u : (u | 0x80000000u);
}
__device__ __forceinline__ float fdec(unsigned e) {
  unsigned u = (e & 0x80000000u) ? (e & 0x7FFFFFFFu) : ~e;
  return __uint_as_float(u);
}

__device__ __forceinline__ void push_cand(unsigned* cnt,
                                          unsigned long long* cand, int row,
                                          float s) {
  unsigned idx = atomicAdd(cnt, 1u);
  if (idx < CAP)
    cand[idx] = ((unsigned long long)(unsigned)row << 32) | __float_as_uint(s);
}

// ---- S1: per-chunk class histogram; block 0 zeroes the candidate count ----
__global__ void k_hist(const int* __restrict__ tgt, int* __restrict__ H,
                       unsigned* __restrict__ cnt) {
  if (blockIdx.x == 0 && threadIdx.x == 0) *cnt = 0u;
  __shared__ int h[NCLS];
  for (int i = threadIdx.x; i < NCLS; i += 128) h[i] = 0;
  __syncthreads();
  atomicAdd(&h[tgt[blockIdx.x * 128 + threadIdx.x]], 1);
  __syncthreads();
  for (int i = threadIdx.x; i < NCLS; i += 128)
    H[blockIdx.x * NCLS + i] = h[i];
}

// ---- S2: scans -> scatter bases, class starts, psim bases (m^2 prefix) ----
__global__ void k_scan(const int* __restrict__ H, int* __restrict__ CB,
                       int* __restrict__ cls_start, int* __restrict__ pbase,
                       int n) {
  __shared__ int wsum[8], wsum2[8];
  const int c = threadIdx.x;  // class, 512 threads
  int t = 0;
#pragma unroll 8
  for (int k = 0; k < 64; ++k) t += H[k * NCLS + c];
  const int t2 = t * t;
  const int lane = c & 63, w = c >> 6;
  int v = t, v2 = t2;
#pragma unroll
  for (int off = 1; off < 64; off <<= 1) {
    int u = __shfl_up(v, off, 64);
    int u2 = __shfl_up(v2, off, 64);
    if (lane >= off) {
      v += u;
      v2 += u2;
    }
  }
  if (lane == 63) {
    wsum[w] = v;
    wsum2[w] = v2;
  }
  __syncthreads();
  if (c < 8) {
    int x = wsum[c], x2 = wsum2[c];
#pragma unroll
    for (int off = 1; off < 8; off <<= 1) {
      int u = __shfl_up(x, off, 64);
      int u2 = __shfl_up(x2, off, 64);
      if (lane >= off) {
        x += u;
        x2 += u2;
      }
    }
    wsum[c] = x;
    wsum2[c] = x2;
  }
  __syncthreads();
  int base = v + ((w > 0) ? wsum[w - 1] : 0) - t;      // excl prefix of m
  int base2 = v2 + ((w > 0) ? wsum2[w - 1] : 0) - t2;  // excl prefix of m^2
  cls_start[c] = base;
  if (c == NCLS - 1) cls_start[NCLS] = n;
  pbase[c] = base2;
  int run = base;
#pragma unroll 8
  for (int k = 0; k < 64; ++k) {
    CB[k * NCLS + c] = run;
    run += H[k * NCLS + c];
  }
}

// ---- S3: stable scatter ----
__global__ void k_scatter(const int* __restrict__ tgt,
                          const int* __restrict__ CB, int* __restrict__ perm) {
  const int c = threadIdx.x;
  int pos = CB[blockIdx.x * NCLS + c];
  const int base = blockIdx.x * 128;
  for (int j = 0; j < 128; ++j) {
    int cls = tgt[base + j];
    if (cls == c) perm[pos++] = base + j;
  }
}

// ---- K1: gather-normalize into fragment-order bf16 + per-row class meta ----
__global__ void k_normB(const float* __restrict__ emb,
                        const int* __restrict__ tgt,
                        const int* __restrict__ perm,
                        const int* __restrict__ cls_start,
                        const int* __restrict__ pbase, uint4* __restrict__ ebB,
                        int* __restrict__ tgtS, int* __restrict__ rowS0,
                        int* __restrict__ rowM, int* __restrict__ rowBase,
                        unsigned* __restrict__ maxNegEnc, int n) {
  const int s = blockIdx.x;
  const int rl = threadIdx.x >> 4;
  const int c = threadIdx.x & 15;
  const int p = s * 16 + rl;
  const int orig = perm[p];
  const float* q = emb + (size_t)orig * D + c * 8;
  float4 v0 = *(const float4*)q;
  float4 v1 = *(const float4*)(q + 4);
  float ss = v0.x * v0.x + v0.y * v0.y + v0.z * v0.z + v0.w * v0.w +
             v1.x * v1.x + v1.y * v1.y + v1.z * v1.z + v1.w * v1.w;
#pragma unroll
  for (int off = 1; off < 16; off <<= 1) ss += __shfl_xor(ss, off, 64);
  float invn = 1.0f / fmaxf(sqrtf(ss), 1e-12f);
  uint4 wv;
  wv.x = (unsigned)f2bf(v0.x * invn) | ((unsigned)f2bf(v0.y * invn) << 16);
  wv.y = (unsigned)f2bf(v0.z * invn) | ((unsigned)f2bf(v0.w * invn) << 16);
  wv.z = (unsigned)f2bf(v1.x * invn) | ((unsigned)f2bf(v1.y * invn) << 16);
  wv.w = (unsigned)f2bf(v1.z * invn) | ((unsigned)f2bf(v1.w * invn) << 16);
  const int ks = c >> 2, g = c & 3;
  ebB[((s * 4 + ks) * 64) + (g * 16 + rl)] = wv;
  if (c == 0) {
    int cls = tgt[orig];
    int s0 = cls_start[cls];
    tgtS[p] = cls;
    rowS0[p] = s0;
    rowM[p] = cls_start[cls + 1] - s0;
    rowBase[p] = pbase[cls];
    maxNegEnc[p] = 0u;  // encoded -inf floor (re-init every launch)
  }
}

// ---- K2: symmetric sweep, 8 waves x (32 rows x 64 cols)/step, 8 chains ----
__global__ __launch_bounds__(512, 2) void k_passN(
    const bf16x8* __restrict__ ebB, const int* __restrict__ tgtS,
    const int* __restrict__ rowS0, const int* __restrict__ rowM,
    const int* __restrict__ rowBase, float* __restrict__ psim,
    unsigned* __restrict__ maxNegEnc, unsigned* __restrict__ cnt,
    unsigned long long* __restrict__ cand, int n) {
  __shared__ char Bs[32768];          // 8 stripes x 4 KB, fragment order
  __shared__ float colbuf[8][8][16];  // [stripe][wave][l15] col-max
  __shared__ int sBuf[16];            // slo/shi per stripe

  const int tid = threadIdx.x;
  const int lane = tid & 63;
  const int w = tid >> 6;  // 0..7
  const int l15 = lane & 15, g = lane >> 4;

  // Triangular decode: tiles (bi, bj) with bj >= 2*bi.
  const int nby = n >> 7;  // 64 col slices
  int t = blockIdx.x, bi = 0, rem = nby;
  while (t >= rem) {
    t -= rem;
    ++bi;
    rem -= 2;
  }
  const int bj = 2 * bi + t;
  const bool colside = (bj >= 2 * bi + 2);  // strictly above: double duty
  const int cs0 = bj * 8;
  const int rbase = bi * 256 + w * 32;  // this wave's 32-row panel

  {  // stage B slice: contiguous 32 KB linear copy (512 threads x 4 iters)
    const char* src = (const char*)ebB + (size_t)cs0 * 4096;
#pragma unroll
    for (int i = 0; i < 4; ++i) {
      __builtin_amdgcn_global_load_lds(
          (const __attribute__((address_space(1))) void*)(src + i * 8192 +
                                                          tid * 16),
          (__attribute__((address_space(3))) void*)(Bs + i * 8192 + tid * 16),
          16, 0, 0);
    }
  }
  if (tid < 16) {  // stripe class ranges into LDS
    int si = tid >> 1, which = tid & 1;
    sBuf[tid] = tgtS[(cs0 + si) * 16 + which * 15];
  }

  const int sA = rbase >> 4;
  const int clo = tgtS[rbase], chi = tgtS[rbase + 31];

  bf16x8 a[2][4];
#pragma unroll
  for (int mt = 0; mt < 2; ++mt)
#pragma unroll
    for (int ks = 0; ks < 4; ++ks)
      a[mt][ks] = ebB[((sA + mt) * 4 + ks) * 64 + lane];

  float accN[2][4];
#pragma unroll
  for (int mt = 0; mt < 2; ++mt)
#pragma unroll
    for (int r = 0; r < 4; ++r) accN[mt][r] = NINF;

  __syncthreads();  // B + sBuf resident

#pragma unroll 1
  for (int ss = 0; ss < 2; ++ss) {
    const int sbase = ss * 4;
    f32x4 acc[4][2];  // [stripe][mt] — 8 independent MFMA chains
#pragma unroll
    for (int st = 0; st < 4; ++st)
#pragma unroll
      for (int mt = 0; mt < 2; ++mt) acc[st][mt] = (f32x4){0.f, 0.f, 0.f, 0.f};

    __builtin_amdgcn_s_setprio(1);
#pragma unroll
    for (int ks = 0; ks < 4; ++ks) {
      // 4 independent B-fragment loads for this k-slice
      bf16x8 b0 = *(const bf16x8*)(Bs + (sbase + 0) * 4096 + ks * 1024 +
                                   lane * 16);
      bf16x8 b1 = *(const bf16x8*)(Bs + (sbase + 1) * 4096 + ks * 1024 +
                                   lane * 16);
      bf16x8 b2 = *(const bf16x8*)(Bs + (sbase + 2) * 4096 + ks * 1024 +
                                   lane * 16);
      bf16x8 b3 = *(const bf16x8*)(Bs + (sbase + 3) * 4096 + ks * 1024 +
                                   lane * 16);
      // 8 MFMAs into 8 distinct chains
      acc[0][0] = __builtin_amdgcn_mfma_f32_16x16x32_bf16(a[0][ks], b0,
                                                          acc[0][0], 0, 0, 0);
      acc[0][1] = __builtin_amdgcn_mfma_f32_16x16x32_bf16(a[1][ks], b0,
                                                          acc[0][1], 0, 0, 0);
      acc[1][0] = __builtin_amdgcn_mfma_f32_16x16x32_bf16(a[0][ks], b1,
                                                          acc[1][0], 0, 0, 0);
      acc[1][1] = __builtin_amdgcn_mfma_f32_16x16x32_bf16(a[1][ks], b1,
                                                          acc[1][1], 0, 0, 0);
      acc[2][0] = __builtin_amdgcn_mfma_f32_16x16x32_bf16(a[0][ks], b2,
                                                          acc[2][0], 0, 0, 0);
      acc[2][1] = __builtin_amdgcn_mfma_f32_16x16x32_bf16(a[1][ks], b2,
                                                          acc[2][1], 0, 0, 0);
      acc[3][0] = __builtin_amdgcn_mfma_f32_16x16x32_bf16(a[0][ks], b3,
                                                          acc[3][0], 0, 0, 0);
      acc[3][1] = __builtin_amdgcn_mfma_f32_16x16x32_bf16(a[1][ks], b3,
                                                          acc[3][1], 0, 0, 0);
    }
    __builtin_amdgcn_s_setprio(0);

    // Epilogue per stripe (same verified dual path as r17).
#pragma unroll
    for (int st = 0; st < 4; ++st) {
      const int si = sbase + st;
      const int cs = cs0 + si;
      const int slo = sBuf[2 * si], shi = sBuf[2 * si + 1];
      const bool dirty = (clo <= shi) && (slo <= chi);
      float colMax;
      if (!dirty) {  // pure negatives
#pragma unroll
        for (int mt = 0; mt < 2; ++mt)
#pragma unroll
          for (int r = 0; r < 4; ++r)
            accN[mt][r] = fmaxf(accN[mt][r], acc[st][mt][r]);
        float m0x = fmaxf(fmaxf(acc[st][0][0], acc[st][0][1]),
                          fmaxf(acc[st][0][2], acc[st][0][3]));
        float m1x = fmaxf(fmaxf(acc[st][1][0], acc[st][1][1]),
                          fmaxf(acc[st][1][2], acc[st][1][3]));
        colMax = fmaxf(m0x, m1x);
        if (__any(colMax > 0.5f)) {  // ~never taken
#pragma unroll
          for (int mt = 0; mt < 2; ++mt)
#pragma unroll
            for (int r = 0; r < 4; ++r)
              if (acc[st][mt][r] > 0.5f) {
                int row = rbase + mt * 16 + g * 4 + r;
                int col = cs * 16 + l15;
                push_cand(cnt, cand, row, acc[st][mt][r]);
                if (colside) push_cand(cnt, cand, col, acc[st][mt][r]);
              }
        }
      } else {  // class-range overlap (rare): psim stores + neg tracking
        const int tc = tgtS[cs * 16 + l15];
        const int col = cs * 16 + l15;
        int4 ta = *(const int4*)(tgtS + rbase + g * 4);
        int4 tb = *(const int4*)(tgtS + rbase + 16 + g * 4);
        int tr[2][4] = {{ta.x, ta.y, ta.z, ta.w}, {tb.x, tb.y, tb.z, tb.w}};
        colMax = NINF;
#pragma unroll
        for (int mt = 0; mt < 2; ++mt)
#pragma unroll
          for (int r = 0; r < 4; ++r) {
            float s = acc[st][mt][r];
            const int row = rbase + mt * 16 + g * 4 + r;
            if (tr[mt][r] == tc) {  // same class: store sim (both sides)
              int s0 = rowS0[row];  // col shares s0/m/base (same class)
              int m = rowM[row];
              int b0_ = rowBase[row];
              psim[b0_ + (row - s0) * m + (col - s0)] = s;
              if (colside) psim[b0_ + (col - s0) * m + (row - s0)] = s;
            } else {
              accN[mt][r] = fmaxf(accN[mt][r], s);
              colMax = fmaxf(colMax, s);
              if (s > 0.5f) {
                push_cand(cnt, cand, row, s);
                if (colside) push_cand(cnt, cand, col, s);
              }
            }
          }
      }
      if (colside) {  // reduce colMax over the 4 g-groups; write LDS
        float v = fmaxf(colMax, __shfl_xor(colMax, 16, 64));
        v = fmaxf(v, __shfl_xor(v, 32, 64));
        if (lane < 16) colbuf[si][w][l15] = v;
      }
    }
  }

  // Row-side: reduce accN over the 16 l15-lanes, deterministic atomicMax.
#pragma unroll
  for (int mt = 0; mt < 2; ++mt)
#pragma unroll
    for (int r = 0; r < 4; ++r) {
      float vn = accN[mt][r];
#pragma unroll
      for (int off = 1; off < 16; off <<= 1)
        vn = fmaxf(vn, __shfl_xor(vn, off, 64));
      if (l15 == 0)
        atomicMax(&maxNegEnc[rbase + mt * 16 + g * 4 + r], fenc(vn));
    }

  // Col-side: combine the 8 waves' col-maxes, one atomicMax per column.
  if (colside) {
    __syncthreads();
    if (tid < 128) {
      int si = tid >> 4, l = tid & 15;
      float v = colbuf[si][0][l];
#pragma unroll
      for (int k = 1; k < 8; ++k) v = fmaxf(v, colbuf[si][k][l]);
      atomicMax(&maxNegEnc[(cs0 + si) * 16 + l], fenc(v));
    }
  }
}

// ---- K3: fused per-row stats + block partial sum ----
__global__ void k_stats(const float* __restrict__ psim,
                        const int* __restrict__ rowS0,
                        const int* __restrict__ rowM,
                        const int* __restrict__ rowBase,
                        const unsigned* __restrict__ maxNegEnc,
                        float* __restrict__ thrNeg, float* __restrict__ bpart,
                        int n) {
  __shared__ float red[256];
  int p = blockIdx.x * 256 + threadIdx.x;
  float contrib = 0.f;
  int m = rowM[p];
  if (m <= 1) {
    thrNeg[p] = 1e30f;  // no positive: row contributes 0; kill candidates
  } else {
    float tp = fdec(maxNegEnc[p]) + MARGIN;  // thr_pos
    int i = p - rowS0[p];
    const float* row = psim + rowBase[p] + (size_t)i * m;
    float mp = NINF, pl = 0.f;
    for (int j = 0; j < m; ++j) {
      if (j == i) continue;  // self
      float s = row[j];
      mp = fmaxf(mp, s);
      pl += (s < tp) ? (1.f - s) : 0.f;
    }
    thrNeg[p] = fmaxf(NEG_FLOOR, mp) - MARGIN;
    contrib = pl;
  }
  red[threadIdx.x] = contrib;
  __syncthreads();
  for (int off = 128; off > 0; off >>= 1) {
    if ((int)threadIdx.x < off) red[threadIdx.x] += red[threadIdx.x + off];
    __syncthreads();
  }
  if (threadIdx.x == 0) bpart[blockIdx.x] = red[0];
}

// ---- K4: deterministic candidate fixup + final scalar ----
__global__ void k_fix(const unsigned* __restrict__ cnt,
                      const unsigned long long* __restrict__ cand,
                      const float* __restrict__ thrNeg,
                      const float* __restrict__ bpart, float* __restrict__ out,
                      int n, int nb) {
  __shared__ unsigned long long buf[CAP];
  __shared__ unsigned long long srt[CAP];
  int k = (int)min(*cnt, (unsigned)CAP);
  for (int i = threadIdx.x; i < k; i += 256) buf[i] = cand[i];
  __syncthreads();
  for (int i = threadIdx.x; i < k; i += 256) {
    unsigned long long v = buf[i];
    int rk = 0;
    for (int j = 0; j < k; ++j) {
      unsigned long long u = buf[j];
      rk += (u < v) || (u == v && j < i);
    }
    srt[rk] = v;
  }
  __syncthreads();
  if (threadIdx.x == 0) {
    float tot = 0.f;
    for (int i = 0; i < nb; ++i) tot += bpart[i];
    for (int i = 0; i < k; ++i) {
      int row = (int)(srt[i] >> 32);
      float s = __uint_as_float((unsigned)srt[i]);
      if (s > thrNeg[row]) tot += s;  // thrNeg=+inf when row has no positive
    }
    out[0] = tot / (float)n;
  }
}

extern "C" void kernel_launch(void* const* d_in, const int* in_sizes, int n_in,
                              void* d_out, int out_size, void* d_ws,
                              size_t ws_size, hipStream_t stream) {
  const float* emb = (const float*)d_in[0];
  const int* tgt = (const int*)d_in[1];
  float* out = (float*)d_out;
  const int n = in_sizes[1];  // 8192

  char* ws = (char*)d_ws;
  uint4* ebB = (uint4*)ws;                         // 2 MB
  float* psim = (float*)(ws + (size_t)n * D * 2);  // 2 MB
  unsigned long long* cand = (unsigned long long*)(psim + PSIM_CAP);  // 16 KB
  float* thrNeg = (float*)(cand + CAP);           // [n]
  float* bpart = thrNeg + n;                      // [32] (pad 64)
  unsigned* maxNegEnc = (unsigned*)(bpart + 64);  // [n]
  unsigned* cnt = maxNegEnc + n;                  // [1] (pad 64)
  int* cls_start = (int*)(cnt + 64);              // [513] (pad 1024)
  int* pbase = cls_start + 1024;                  // [512] (pad 1024)
  int* H = pbase + 1024;                          // [64][512]
  int* CB = H + 64 * NCLS;                        // [64][512]
  int* perm = CB + 64 * NCLS;                     // [n]
  int* tgtS = perm + n;                           // [n]
  int* rowS0 = tgtS + n;                          // [n]
  int* rowM = rowS0 + n;                          // [n]
  int* rowBase = rowM + n;                        // [n]

  k_hist<<<n / 128, 128, 0, stream>>>(tgt, H, cnt);
  k_scan<<<1, NCLS, 0, stream>>>(H, CB, cls_start, pbase, n);
  k_scatter<<<n / 128, NCLS, 0, stream>>>(tgt, CB, perm);
  k_normB<<<n / 16, 256, 0, stream>>>(emb, tgt, perm, cls_start, pbase, ebB,
                                      tgtS, rowS0, rowM, rowBase, maxNegEnc,
                                      n);

  const int nbx = n / 256, nby = n / 128;
  const int tblocks = nbx * nby - nbx * (nbx - 1);  // 1056 for n=8192
  k_passN<<<tblocks, 512, 0, stream>>>((const bf16x8*)ebB, tgtS, rowS0, rowM,
                                       rowBase, psim, maxNegEnc, cnt, cand,
                                       n);
  k_stats<<<n / 256, 256, 0, stream>>>(psim, rowS0, rowM, rowBase, maxNegEnc,
                                       thrNeg, bpart, n);
  k_fix<<<1, 256, 0, stream>>>(cnt, cand, thrNeg, bpart, out, n, n / 256);
}

// Round 19
// 60.357 us; speedup vs baseline: 1.2958x; 1.2958x over previous
//
#include <hip/hip_runtime.h>

// BatchWiseTripletLoss: n=8192, d=128, 512 classes, scalar output.
// Round-19: sweep reverted to the round-17 structure (best measured:
// triangular symmetric sweep, 8 waves x 32 rows, LDS colbuf, atomicMax,
// compact unroll-1 loop; r18's 8-chain ILP variant regressed 40->47.6us).
// Aux pipeline consolidated 7->6 kernels:
//  - k_histrank: per-chunk class histogram + stable in-chunk rank (LDS
//    scan), zeroes maxNegEnc and the candidate count. Replaces k_hist and
//    enables deleting k_scatter.
//  - k_normS: normalizes ORIGINAL rows (coalesced emb reads) and
//    scatter-writes fragments to sorted positions pos = CB[chunk][cls] +
//    rnk[orig]; also writes per-sorted-row class metadata.
// launch_bounds(512,2) on the sweep: 256-reg budget (the 128-reg cap of
// (256,4)/(512,4) spilled catastrophically in rounds 3/6/11).

#define D 128
#define NCLS 512
#define CAP 2048               // negative-candidate capacity (expected ~0)
#define PSIM_CAP (512 * 1024)  // sum m^2 ~ 139K expected; 2MB safety
#define MARGIN 0.1f
#define NEG_FLOOR 0.6f
#define NINF -1e30f

typedef short bf16x8 __attribute__((ext_vector_type(8)));
typedef float f32x4 __attribute__((ext_vector_type(4)));

__device__ __forceinline__ unsigned short f2bf(float f) {
  unsigned u = __float_as_uint(f);
  u += 0x7FFFu + ((u >> 16) & 1u);
  return (unsigned short)(u >> 16);
}

// Order-monotonic float<->uint encoding (for atomicMax).
__device__ __forceinline__ unsigned fenc(float f) {
  unsigned u = __float_as_uint(f);
  return (u & 0x80000000u) ? ~u : (u | 0x80000000u);
}
__device__ __forceinline__ float fdec(unsigned e) {
  unsigned u = (e & 0x80000000u) ? (e & 0x7FFFFFFFu) : ~e;
  return __uint_as_float(u);
}

__device__ __forceinline__ void push_cand(unsigned* cnt,
                                          unsigned long long* cand, int row,
                                          float s) {
  unsigned idx = atomicAdd(cnt, 1u);
  if (idx < CAP)
    cand[idx] = ((unsigned long long)(unsigned)row << 32) | __float_as_uint(s);
}

// ---- S1: per-chunk histogram + stable in-chunk rank; zero aux state ----
__global__ void k_histrank(const int* __restrict__ tgt, int* __restrict__ H,
                           int* __restrict__ rnk,
                           unsigned* __restrict__ maxNegEnc,
                           unsigned* __restrict__ cnt) {
  __shared__ int cls[128];
  __shared__ int h[NCLS];
  const int chunk = blockIdx.x;  // 64 chunks x 128 rows
  const int tid = threadIdx.x;   // 128 threads
  const int i = chunk * 128 + tid;
  if (chunk == 0 && tid == 0) *cnt = 0u;
  cls[tid] = tgt[i];
  for (int k = tid; k < NCLS; k += 128) h[k] = 0;
  __syncthreads();
  const int c = cls[tid];
  atomicAdd(&h[c], 1);
  int r = 0;
  for (int j = 0; j < tid; ++j) r += (cls[j] == c);  // stable in-chunk rank
  rnk[i] = r;
  maxNegEnc[i] = 0u;  // encoded -inf floor (re-init every launch)
  __syncthreads();
  for (int k = tid; k < NCLS; k += 128) H[chunk * NCLS + k] = h[k];
}

// ---- S2: scans -> per-chunk scatter bases, class starts, psim bases ----
__global__ void k_scan(const int* __restrict__ H, int* __restrict__ CB,
                       int* __restrict__ cls_start, int* __restrict__ pbase,
                       int n) {
  __shared__ int wsum[8], wsum2[8];
  const int c = threadIdx.x;  // class, 512 threads
  int t = 0;
#pragma unroll 8
  for (int k = 0; k < 64; ++k) t += H[k * NCLS + c];
  const int t2 = t * t;
  const int lane = c & 63, w = c >> 6;
  int v = t, v2 = t2;
#pragma unroll
  for (int off = 1; off < 64; off <<= 1) {
    int u = __shfl_up(v, off, 64);
    int u2 = __shfl_up(v2, off, 64);
    if (lane >= off) {
      v += u;
      v2 += u2;
    }
  }
  if (lane == 63) {
    wsum[w] = v;
    wsum2[w] = v2;
  }
  __syncthreads();
  if (c < 8) {
    int x = wsum[c], x2 = wsum2[c];
#pragma unroll
    for (int off = 1; off < 8; off <<= 1) {
      int u = __shfl_up(x, off, 64);
      int u2 = __shfl_up(x2, off, 64);
      if (lane >= off) {
        x += u;
        x2 += u2;
      }
    }
    wsum[c] = x;
    wsum2[c] = x2;
  }
  __syncthreads();
  int base = v + ((w > 0) ? wsum[w - 1] : 0) - t;      // excl prefix of m
  int base2 = v2 + ((w > 0) ? wsum2[w - 1] : 0) - t2;  // excl prefix of m^2
  cls_start[c] = base;
  if (c == NCLS - 1) cls_start[NCLS] = n;
  pbase[c] = base2;
  int run = base;
#pragma unroll 8
  for (int k = 0; k < 64; ++k) {
    CB[k * NCLS + c] = run;
    run += H[k * NCLS + c];
  }
}

// ---- K1: normalize ORIGINAL rows, scatter-write to sorted positions ----
// Coalesced emb reads; scattered 16B fragment writes. Sorted position:
// pos = CB[chunk][cls] + rnk[orig].
__global__ void k_normS(const float* __restrict__ emb,
                        const int* __restrict__ tgt,
                        const int* __restrict__ rnk, const int* __restrict__ CB,
                        const int* __restrict__ cls_start,
                        const int* __restrict__ pbase, uint4* __restrict__ ebB,
                        int* __restrict__ tgtS, int* __restrict__ rowS0,
                        int* __restrict__ rowM, int* __restrict__ rowBase,
                        int n) {
  const int s = blockIdx.x;          // original 16-row stripe
  const int rl = threadIdx.x >> 4;   // row within stripe
  const int c16 = threadIdx.x & 15;  // 16B chunk within row
  const int orig = s * 16 + rl;
  const float* q = emb + (size_t)orig * D + c16 * 8;
  float4 v0 = *(const float4*)q;
  float4 v1 = *(const float4*)(q + 4);
  float ss = v0.x * v0.x + v0.y * v0.y + v0.z * v0.z + v0.w * v0.w +
             v1.x * v1.x + v1.y * v1.y + v1.z * v1.z + v1.w * v1.w;
#pragma unroll
  for (int off = 1; off < 16; off <<= 1) ss += __shfl_xor(ss, off, 64);
  float invn = 1.0f / fmaxf(sqrtf(ss), 1e-12f);
  uint4 wv;
  wv.x = (unsigned)f2bf(v0.x * invn) | ((unsigned)f2bf(v0.y * invn) << 16);
  wv.y = (unsigned)f2bf(v0.z * invn) | ((unsigned)f2bf(v0.w * invn) << 16);
  wv.z = (unsigned)f2bf(v1.x * invn) | ((unsigned)f2bf(v1.y * invn) << 16);
  wv.w = (unsigned)f2bf(v1.z * invn) | ((unsigned)f2bf(v1.w * invn) << 16);
  const int cls = tgt[orig];
  const int chunk = orig >> 7;
  const int pos = CB[chunk * NCLS + cls] + rnk[orig];  // sorted row index
  const int sstripe = pos >> 4, srl = pos & 15;
  const int ks = c16 >> 2, g = c16 & 3;
  ebB[((sstripe * 4 + ks) * 64) + (g * 16 + srl)] = wv;
  if (c16 == 0) {
    int s0 = cls_start[cls];
    tgtS[pos] = cls;
    rowS0[pos] = s0;
    rowM[pos] = cls_start[cls + 1] - s0;
    rowBase[pos] = pbase[cls];
  }
}

// ---- K2: symmetric sweep, 8 waves x 32 rows, compact unroll-1 loop ----
__global__ __launch_bounds__(512, 2) void k_passN(
    const bf16x8* __restrict__ ebB, const int* __restrict__ tgtS,
    const int* __restrict__ rowS0, const int* __restrict__ rowM,
    const int* __restrict__ rowBase, float* __restrict__ psim,
    unsigned* __restrict__ maxNegEnc, unsigned* __restrict__ cnt,
    unsigned long long* __restrict__ cand, int n) {
  __shared__ char Bs[32768];          // 8 stripes x 4 KB, fragment order
  __shared__ float colbuf[8][8][16];  // [stripe][wave][l15] col-max
  __shared__ int sBuf[16];            // slo/shi per stripe

  const int tid = threadIdx.x;
  const int lane = tid & 63;
  const int w = tid >> 6;  // 0..7
  const int l15 = lane & 15, g = lane >> 4;

  // Triangular decode: tiles (bi, bj) with bj >= 2*bi.
  const int nby = n >> 7;  // 64 col slices
  int t = blockIdx.x, bi = 0, rem = nby;
  while (t >= rem) {
    t -= rem;
    ++bi;
    rem -= 2;
  }
  const int bj = 2 * bi + t;
  const bool colside = (bj >= 2 * bi + 2);  // strictly above: double duty
  const int cs0 = bj * 8;
  const int rbase = bi * 256 + w * 32;  // this wave's 32-row panel

  {  // stage B slice: contiguous 32 KB linear copy (512 threads x 4 iters)
    const char* src = (const char*)ebB + (size_t)cs0 * 4096;
#pragma unroll
    for (int i = 0; i < 4; ++i) {
      __builtin_amdgcn_global_load_lds(
          (const __attribute__((address_space(1))) void*)(src + i * 8192 +
                                                          tid * 16),
          (__attribute__((address_space(3))) void*)(Bs + i * 8192 + tid * 16),
          16, 0, 0);
    }
  }
  if (tid < 16) {  // stripe class ranges into LDS
    int si = tid >> 1, which = tid & 1;
    sBuf[tid] = tgtS[(cs0 + si) * 16 + which * 15];
  }

  const int sA = rbase >> 4;
  const int clo = tgtS[rbase], chi = tgtS[rbase + 31];

  bf16x8 a[2][4];
#pragma unroll
  for (int mt = 0; mt < 2; ++mt)
#pragma unroll
    for (int ks = 0; ks < 4; ++ks)
      a[mt][ks] = ebB[((sA + mt) * 4 + ks) * 64 + lane];

  float accN[2][4];
#pragma unroll
  for (int mt = 0; mt < 2; ++mt)
#pragma unroll
    for (int r = 0; r < 4; ++r) accN[mt][r] = NINF;

  __syncthreads();  // B + sBuf resident

#pragma unroll 1
  for (int si = 0; si < 8; ++si) {
    const int cs = cs0 + si;
    bf16x8 b[4];
#pragma unroll
    for (int ks = 0; ks < 4; ++ks)
      b[ks] = *(const bf16x8*)(Bs + si * 4096 + ks * 1024 + lane * 16);
    const int slo = sBuf[2 * si], shi = sBuf[2 * si + 1];

    f32x4 acc[2];
#pragma unroll
    for (int mt = 0; mt < 2; ++mt) acc[mt] = (f32x4){0.f, 0.f, 0.f, 0.f};
    __builtin_amdgcn_s_setprio(1);
#pragma unroll
    for (int ks = 0; ks < 4; ++ks)
#pragma unroll
      for (int mt = 0; mt < 2; ++mt)
        acc[mt] = __builtin_amdgcn_mfma_f32_16x16x32_bf16(a[mt][ks], b[ks],
                                                          acc[mt], 0, 0, 0);
    __builtin_amdgcn_s_setprio(0);

    const bool dirty = (clo <= shi) && (slo <= chi);
    float colMax;  // per-lane max over this lane's 8 (neg) elements
    if (!dirty) {  // pure negatives: 8 fmax + tree
#pragma unroll
      for (int mt = 0; mt < 2; ++mt)
#pragma unroll
        for (int r = 0; r < 4; ++r)
          accN[mt][r] = fmaxf(accN[mt][r], acc[mt][r]);
      float m0x =
          fmaxf(fmaxf(acc[0][0], acc[0][1]), fmaxf(acc[0][2], acc[0][3]));
      float m1x =
          fmaxf(fmaxf(acc[1][0], acc[1][1]), fmaxf(acc[1][2], acc[1][3]));
      colMax = fmaxf(m0x, m1x);
      if (__any(colMax > 0.5f)) {  // ~never taken
#pragma unroll
        for (int mt = 0; mt < 2; ++mt)
#pragma unroll
          for (int r = 0; r < 4; ++r)
            if (acc[mt][r] > 0.5f) {
              int row = rbase + mt * 16 + g * 4 + r;
              int col = cs * 16 + l15;
              push_cand(cnt, cand, row, acc[mt][r]);
              if (colside) push_cand(cnt, cand, col, acc[mt][r]);
            }
      }
    } else {  // class-range overlap (rare): psim stores + neg tracking
      const int tc = tgtS[cs * 16 + l15];
      const int col = cs * 16 + l15;
      int4 ta = *(const int4*)(tgtS + rbase + g * 4);
      int4 tb = *(const int4*)(tgtS + rbase + 16 + g * 4);
      int tr[2][4] = {{ta.x, ta.y, ta.z, ta.w}, {tb.x, tb.y, tb.z, tb.w}};
      colMax = NINF;
#pragma unroll
      for (int mt = 0; mt < 2; ++mt)
#pragma unroll
        for (int r = 0; r < 4; ++r) {
          float s = acc[mt][r];
          const int row = rbase + mt * 16 + g * 4 + r;
          if (tr[mt][r] == tc) {  // same class: store sim (both sides)
            int s0 = rowS0[row];  // col shares s0/m/base (same class)
            int m = rowM[row];
            int b0 = rowBase[row];
            psim[b0 + (row - s0) * m + (col - s0)] = s;
            if (colside) psim[b0 + (col - s0) * m + (row - s0)] = s;
          } else {
            accN[mt][r] = fmaxf(accN[mt][r], s);
            colMax = fmaxf(colMax, s);
            if (s > 0.5f) {
              push_cand(cnt, cand, row, s);
              if (colside) push_cand(cnt, cand, col, s);
            }
          }
        }
    }
    if (colside) {  // reduce colMax over the 4 g-groups; g==0 writes LDS
      float v = fmaxf(colMax, __shfl_xor(colMax, 16, 64));
      v = fmaxf(v, __shfl_xor(v, 32, 64));
      if (lane < 16) colbuf[si][w][l15] = v;
    }
  }

  // Row-side: reduce accN over the 16 l15-lanes, deterministic atomicMax.
#pragma unroll
  for (int mt = 0; mt < 2; ++mt)
#pragma unroll
    for (int r = 0; r < 4; ++r) {
      float vn = accN[mt][r];
#pragma unroll
      for (int off = 1; off < 16; off <<= 1)
        vn = fmaxf(vn, __shfl_xor(vn, off, 64));
      if (l15 == 0)
        atomicMax(&maxNegEnc[rbase + mt * 16 + g * 4 + r], fenc(vn));
    }

  // Col-side: combine the 8 waves' col-maxes, one atomicMax per column.
  if (colside) {
    __syncthreads();
    if (tid < 128) {
      int si = tid >> 4, l = tid & 15;
      float v = colbuf[si][0][l];
#pragma unroll
      for (int k = 1; k < 8; ++k) v = fmaxf(v, colbuf[si][k][l]);
      atomicMax(&maxNegEnc[(cs0 + si) * 16 + l], fenc(v));
    }
  }
}

// ---- K3: fused per-row stats + block partial sum ----
__global__ void k_stats(const float* __restrict__ psim,
                        const int* __restrict__ rowS0,
                        const int* __restrict__ rowM,
                        const int* __restrict__ rowBase,
                        const unsigned* __restrict__ maxNegEnc,
                        float* __restrict__ thrNeg, float* __restrict__ bpart,
                        int n) {
  __shared__ float red[256];
  int p = blockIdx.x * 256 + threadIdx.x;
  float contrib = 0.f;
  int m = rowM[p];
  if (m <= 1) {
    thrNeg[p] = 1e30f;  // no positive: row contributes 0; kill candidates
  } else {
    float tp = fdec(maxNegEnc[p]) + MARGIN;  // thr_pos
    int i = p - rowS0[p];
    const float* row = psim + rowBase[p] + (size_t)i * m;
    float mp = NINF, pl = 0.f;
    for (int j = 0; j < m; ++j) {
      if (j == i) continue;  // self
      float s = row[j];
      mp = fmaxf(mp, s);
      pl += (s < tp) ? (1.f - s) : 0.f;
    }
    thrNeg[p] = fmaxf(NEG_FLOOR, mp) - MARGIN;
    contrib = pl;
  }
  red[threadIdx.x] = contrib;
  __syncthreads();
  for (int off = 128; off > 0; off >>= 1) {
    if ((int)threadIdx.x < off) red[threadIdx.x] += red[threadIdx.x + off];
    __syncthreads();
  }
  if (threadIdx.x == 0) bpart[blockIdx.x] = red[0];
}

// ---- K4: deterministic candidate fixup + final scalar ----
__global__ void k_fix(const unsigned* __restrict__ cnt,
                      const unsigned long long* __restrict__ cand,
                      const float* __restrict__ thrNeg,
                      const float* __restrict__ bpart, float* __restrict__ out,
                      int n, int nb) {
  __shared__ unsigned long long buf[CAP];
  __shared__ unsigned long long srt[CAP];
  int k = (int)min(*cnt, (unsigned)CAP);
  for (int i = threadIdx.x; i < k; i += 256) buf[i] = cand[i];
  __syncthreads();
  for (int i = threadIdx.x; i < k; i += 256) {
    unsigned long long v = buf[i];
    int rk = 0;
    for (int j = 0; j < k; ++j) {
      unsigned long long u = buf[j];
      rk += (u < v) || (u == v && j < i);
    }
    srt[rk] = v;
  }
  __syncthreads();
  if (threadIdx.x == 0) {
    float tot = 0.f;
    for (int i = 0; i < nb; ++i) tot += bpart[i];
    for (int i = 0; i < k; ++i) {
      int row = (int)(srt[i] >> 32);
      float s = __uint_as_float((unsigned)srt[i]);
      if (s > thrNeg[row]) tot += s;  // thrNeg=+inf when row has no positive
    }
    out[0] = tot / (float)n;
  }
}

extern "C" void kernel_launch(void* const* d_in, const int* in_sizes, int n_in,
                              void* d_out, int out_size, void* d_ws,
                              size_t ws_size, hipStream_t stream) {
  const float* emb = (const float*)d_in[0];
  const int* tgt = (const int*)d_in[1];
  float* out = (float*)d_out;
  const int n = in_sizes[1];  // 8192

  char* ws = (char*)d_ws;
  uint4* ebB = (uint4*)ws;                         // 2 MB
  float* psim = (float*)(ws + (size_t)n * D * 2);  // 2 MB
  unsigned long long* cand = (unsigned long long*)(psim + PSIM_CAP);  // 16 KB
  float* thrNeg = (float*)(cand + CAP);           // [n]
  float* bpart = thrNeg + n;                      // [32] (pad 64)
  unsigned* maxNegEnc = (unsigned*)(bpart + 64);  // [n]
  unsigned* cnt = maxNegEnc + n;                  // [1] (pad 64)
  int* cls_start = (int*)(cnt + 64);              // [513] (pad 1024)
  int* pbase = cls_start + 1024;                  // [512] (pad 1024)
  int* H = pbase + 1024;                          // [64][512]
  int* CB = H + 64 * NCLS;                        // [64][512]
  int* rnk = CB + 64 * NCLS;                      // [n]
  int* tgtS = rnk + n;                            // [n]
  int* rowS0 = tgtS + n;                          // [n]
  int* rowM = rowS0 + n;                          // [n]
  int* rowBase = rowM + n;                        // [n]

  k_histrank<<<n / 128, 128, 0, stream>>>(tgt, H, rnk, maxNegEnc, cnt);
  k_scan<<<1, NCLS, 0, stream>>>(H, CB, cls_start, pbase, n);
  k_normS<<<n / 16, 256, 0, stream>>>(emb, tgt, rnk, CB, cls_start, pbase,
                                      ebB, tgtS, rowS0, rowM, rowBase, n);

  const int nbx = n / 256, nby = n / 128;
  const int tblocks = nbx * nby - nbx * (nbx - 1);  // 1056 for n=8192
  k_passN<<<tblocks, 512, 0, stream>>>((const bf16x8*)ebB, tgtS, rowS0, rowM,
                                       rowBase, psim, maxNegEnc, cnt, cand,
                                       n);
  k_stats<<<n / 256, 256, 0, stream>>>(psim, rowS0, rowM, rowBase, maxNegEnc,
                                       thrNeg, bpart, n);
  k_fix<<<1, 256, 0, stream>>>(cnt, cand, thrNeg, bpart, out, n, n / 256);
}